// Round 1
// baseline (109.591 us; speedup 1.0000x reference)
//
#include <hip/hip_runtime.h>

#define NPATCH 196
#define BLK 256

__global__ __launch_bounds__(BLK) void quanv_fused(
    const float* __restrict__ x,        // [B, 784]
    const float* __restrict__ vp,       // [2,4] var_params
    const float* __restrict__ map_w,    // [8,4]
    const float* __restrict__ map_b,    // [8]
    const float* __restrict__ lin_w,    // [10, 1568]
    const float* __restrict__ lin_b,    // [10]
    float* __restrict__ out)            // [B, 10]
{
    __shared__ float s_img[784];
    __shared__ float s_part[4][10];

    const int b   = blockIdx.x;
    const int tid = threadIdx.x;

    // Stage the image into LDS, coalesced.
    const float* img = x + (size_t)b * 784;
    #pragma unroll
    for (int i = 0; i < 4; ++i) {
        int idx = tid + i * BLK;
        if (idx < 784) s_img[idx] = img[idx];
    }
    __syncthreads();

    float lg[10];
    #pragma unroll
    for (int k = 0; k < 10; ++k) lg[k] = 0.0f;

    if (tid < NPATCH) {
        const int py = tid / 14;
        const int px = tid - py * 14;
        const int r0 = (2 * py) * 28 + 2 * px;
        const float inv255 = 1.0f / 255.0f;

        // patch order: (r,c) = (0,0),(0,1),(1,0),(1,1)
        float ang[4];
        ang[0] = s_img[r0]      * inv255;
        ang[1] = s_img[r0 + 1]  * inv255;
        ang[2] = s_img[r0 + 28] * inv255;
        ang[3] = s_img[r0 + 29] * inv255;

        // Layers 1+2: RY(ang)RY(v0) on |0> per wire -> product state angles.
        float c[4], s[4];
        #pragma unroll
        for (int i = 0; i < 4; ++i) {
            float half = (ang[i] + vp[i]) * 0.5f;
            __sincosf(half, &s[i], &c[i]);
        }

        // Product state with the 3 CNOTs (pure index permutation) folded in:
        // st[b0b1b2b3] = q0(b0) q1(b0^b1) q2(b1^b2) q3(b2^b3)
        float st[16];
        #pragma unroll
        for (int idx = 0; idx < 16; ++idx) {
            const int b0 = (idx >> 3) & 1;
            const int b1 = (idx >> 2) & 1;
            const int b2 = (idx >> 1) & 1;
            const int b3 = idx & 1;
            const float q0 = b0        ? s[0] : c[0];
            const float q1 = (b0 ^ b1) ? s[1] : c[1];
            const float q2 = (b1 ^ b2) ? s[2] : c[2];
            const float q3 = (b2 ^ b3) ? s[3] : c[3];
            st[idx] = q0 * q1 * q2 * q3;
        }

        // Final RY layer (uniform angles vp[4..7]).
        #pragma unroll
        for (int w = 0; w < 4; ++w) {
            float C, S;
            __sincosf(vp[4 + w] * 0.5f, &S, &C);
            const int stride = 8 >> w;
            #pragma unroll
            for (int i = 0; i < 16; ++i) {
                if ((i & stride) == 0) {
                    const float x0 = st[i], x1 = st[i | stride];
                    st[i]          = C * x0 - S * x1;
                    st[i | stride] = S * x0 + C * x1;
                }
            }
        }

        // <Z_w> = sum_b st[b]^2 * (+1 if bit w ==0 else -1)
        float p2[16];
        #pragma unroll
        for (int i = 0; i < 16; ++i) p2[i] = st[i] * st[i];
        float meas[4];
        #pragma unroll
        for (int w = 0; w < 4; ++w) {
            const int stride = 8 >> w;
            float m = 0.0f;
            #pragma unroll
            for (int i = 0; i < 16; ++i) m += (i & stride) ? -p2[i] : p2[i];
            meas[w] = m;
        }

        // feat[j] = meas . map_w[j,:] + map_b[j]
        float feat[8];
        #pragma unroll
        for (int j = 0; j < 8; ++j) {
            float f = map_b[j];
            #pragma unroll
            for (int i = 0; i < 4; ++i) f = fmaf(meas[i], map_w[j * 4 + i], f);
            feat[j] = f;
        }

        // partial logits: lg[k] = feat . lin_w[k, tid*8 : tid*8+8]
        const float* lw = lin_w + tid * 8;
        #pragma unroll
        for (int k = 0; k < 10; ++k) {
            const float4 w0 = *(const float4*)(lw + k * 1568);
            const float4 w1 = *(const float4*)(lw + k * 1568 + 4);
            lg[k] = feat[0] * w0.x + feat[1] * w0.y + feat[2] * w0.z + feat[3] * w0.w
                  + feat[4] * w1.x + feat[5] * w1.y + feat[6] * w1.z + feat[7] * w1.w;
        }
    }

    // Block reduction of lg[10] (inactive threads contribute zeros).
    #pragma unroll
    for (int k = 0; k < 10; ++k) {
        float v = lg[k];
        #pragma unroll
        for (int off = 32; off > 0; off >>= 1)
            v += __shfl_xor(v, off, 64);
        lg[k] = v;
    }
    const int wave = tid >> 6;
    if ((tid & 63) == 0) {
        #pragma unroll
        for (int k = 0; k < 10; ++k) s_part[wave][k] = lg[k];
    }
    __syncthreads();

    if (tid == 0) {
        float logits[10];
        float mx = -1e30f;
        #pragma unroll
        for (int k = 0; k < 10; ++k) {
            logits[k] = lin_b[k] + s_part[0][k] + s_part[1][k] + s_part[2][k] + s_part[3][k];
            mx = fmaxf(mx, logits[k]);
        }
        float sum = 0.0f;
        #pragma unroll
        for (int k = 0; k < 10; ++k) sum += expf(logits[k] - mx);
        const float lse = mx + logf(sum);
        float* o = out + (size_t)b * 10;
        #pragma unroll
        for (int k = 0; k < 10; ++k) o[k] = logits[k] - lse;
    }
}

extern "C" void kernel_launch(void* const* d_in, const int* in_sizes, int n_in,
                              void* d_out, int out_size, void* d_ws, size_t ws_size,
                              hipStream_t stream) {
    const float* x     = (const float*)d_in[0];
    const float* vp    = (const float*)d_in[1];
    const float* map_w = (const float*)d_in[2];
    const float* map_b = (const float*)d_in[3];
    const float* lin_w = (const float*)d_in[4];
    const float* lin_b = (const float*)d_in[5];
    float* out = (float*)d_out;

    const int B = in_sizes[0] / 784;
    quanv_fused<<<B, BLK, 0, stream>>>(x, vp, map_w, map_b, lin_w, lin_b, out);
}

// Round 2
// 101.207 us; speedup vs baseline: 1.0828x; 1.0828x over previous
//
#include <hip/hip_runtime.h>

// ws layout (floats):
//   [0..3]   cva  = cos(vp[0][i])
//   [4..7]   sva  = sin(vp[0][i])
//   [8..11]  cth  = cos(vp[1][w])
//   [12..15] sth  = sin(vp[1][w])
//   [16..25] folded bias b'[k] = lin_b[k] + sum_p sum_j lin_w[k,p*8+j]*map_b[j]
//   [64..]   M[196][10][4]: M[p][k][i] = sum_j lin_w[k,p*8+j]*map_w[j*4+i]

__global__ __launch_bounds__(256) void quanv_precompute(
    const float* __restrict__ vp,
    const float* __restrict__ map_w,
    const float* __restrict__ map_b,
    const float* __restrict__ lin_w,
    const float* __restrict__ lin_b,
    float* __restrict__ ws)
{
    const int tid = threadIdx.x;
    __shared__ float s_part[4][10];

    float pb[10];
    #pragma unroll
    for (int k = 0; k < 10; ++k) pb[k] = 0.0f;

    if (tid < 196) {
        float mw[32];
        #pragma unroll
        for (int j = 0; j < 8; ++j) {
            const float4 m4 = *(const float4*)(map_w + j * 4);
            mw[j * 4 + 0] = m4.x; mw[j * 4 + 1] = m4.y;
            mw[j * 4 + 2] = m4.z; mw[j * 4 + 3] = m4.w;
        }
        float mb[8];
        #pragma unroll
        for (int j = 0; j < 8; ++j) mb[j] = map_b[j];

        #pragma unroll
        for (int k = 0; k < 10; ++k) {
            const float* lw = lin_w + k * 1568 + tid * 8;
            const float4 w0 = *(const float4*)lw;
            const float4 w1 = *(const float4*)(lw + 4);
            const float l[8] = {w0.x, w0.y, w0.z, w0.w, w1.x, w1.y, w1.z, w1.w};
            float4 m = make_float4(0.f, 0.f, 0.f, 0.f);
            #pragma unroll
            for (int j = 0; j < 8; ++j) {
                m.x = fmaf(l[j], mw[j * 4 + 0], m.x);
                m.y = fmaf(l[j], mw[j * 4 + 1], m.y);
                m.z = fmaf(l[j], mw[j * 4 + 2], m.z);
                m.w = fmaf(l[j], mw[j * 4 + 3], m.w);
                pb[k] = fmaf(l[j], mb[j], pb[k]);
            }
            *(float4*)(ws + 64 + tid * 40 + k * 4) = m;
        }
    }

    // block-reduce pb[10] (inactive threads contribute zeros)
    #pragma unroll
    for (int k = 0; k < 10; ++k) {
        float v = pb[k];
        #pragma unroll
        for (int off = 32; off; off >>= 1) v += __shfl_xor(v, off, 64);
        pb[k] = v;
    }
    if ((tid & 63) == 0) {
        #pragma unroll
        for (int k = 0; k < 10; ++k) s_part[tid >> 6][k] = pb[k];
    }
    __syncthreads();
    if (tid < 10)
        ws[16 + tid] = lin_b[tid] + s_part[0][tid] + s_part[1][tid]
                                  + s_part[2][tid] + s_part[3][tid];
    if (tid == 0) {
        #pragma unroll
        for (int i = 0; i < 4; ++i) {
            ws[i]      = cosf(vp[i]);     ws[4 + i]  = sinf(vp[i]);
            ws[8 + i]  = cosf(vp[4 + i]); ws[12 + i] = sinf(vp[4 + i]);
        }
    }
}

__device__ __forceinline__ void process_patch(
    int p, const float* __restrict__ img, const float* __restrict__ M,
    const float cva[4], const float sva[4],
    const float cth[4], const float sth[4], float lg[10])
{
    const int py = p / 14;
    const int px = p - py * 14;
    const int r0 = py * 56 + px * 2;
    const float2 t01 = *(const float2*)(img + r0);
    const float2 t23 = *(const float2*)(img + r0 + 28);
    const float t[4] = {t01.x, t01.y, t23.x, t23.y};

    // C_i = cos(t/255 + a_i), S_i = sin(t/255 + a_i) via Taylor (t/255 < 0.004)
    float C[4], S[4];
    #pragma unroll
    for (int i = 0; i < 4; ++i) {
        const float a  = t[i] * (1.0f / 255.0f);
        const float a2 = a * a;
        const float ct = fmaf(a2, -0.5f, 1.0f);
        const float st = a * fmaf(a2, -1.0f / 6.0f, 1.0f);
        C[i] = fmaf(cva[i], ct, -sva[i] * st);
        S[i] = fmaf(sva[i], ct,  cva[i] * st);
    }

    // closed-form <Z_w> after CNOT chain + final RY layer
    const float P1 = C[0] * C[1], P2 = P1 * C[2], P3 = P2 * C[3];
    const float X0 = S[0] * S[1], X1 = S[1] * S[2], X2 = S[2] * S[3];
    float meas[4];
    meas[0] = fmaf(cth[0], C[0], -sth[0] * X0);
    meas[1] = fmaf(cth[1], P1,   -sth[1] * X1);
    meas[2] = fmaf(cth[2], P2,   -sth[2] * X2);
    meas[3] = fmaf(cth[3], P3,   -sth[3] * S[3]);

    const float4* Mp = (const float4*)(M + p * 40);
    #pragma unroll
    for (int k = 0; k < 10; ++k) {
        const float4 w = Mp[k];
        lg[k] += meas[0] * w.x + meas[1] * w.y + meas[2] * w.z + meas[3] * w.w;
    }
}

// one wave per image; 4 images per block; no LDS, no barriers
__global__ __launch_bounds__(256, 8) void quanv_main(
    const float* __restrict__ x,
    const float* __restrict__ ws,
    float* __restrict__ out, int B)
{
    const int lane = threadIdx.x & 63;
    const int b = blockIdx.x * 4 + (threadIdx.x >> 6);
    if (b >= B) return;

    float cva[4], sva[4], cth[4], sth[4];
    #pragma unroll
    for (int i = 0; i < 4; ++i) {
        cva[i] = ws[i];     sva[i] = ws[4 + i];
        cth[i] = ws[8 + i]; sth[i] = ws[12 + i];
    }

    const float* img = x + (size_t)b * 784;
    const float* M = ws + 64;

    float lg[10];
    #pragma unroll
    for (int k = 0; k < 10; ++k) lg[k] = 0.0f;

    process_patch(lane,       img, M, cva, sva, cth, sth, lg);
    process_patch(lane + 64,  img, M, cva, sva, cth, sth, lg);
    process_patch(lane + 128, img, M, cva, sva, cth, sth, lg);
    if (lane < 4)
        process_patch(lane + 192, img, M, cva, sva, cth, sth, lg);

    // wave reduction: butterfly leaves full sums in every lane
    #pragma unroll
    for (int k = 0; k < 10; ++k) {
        float v = lg[k];
        #pragma unroll
        for (int off = 32; off; off >>= 1) v += __shfl_xor(v, off, 64);
        lg[k] = v;
    }

    if (lane == 0) {
        float logits[10];
        float mx = -1e30f;
        #pragma unroll
        for (int k = 0; k < 10; ++k) {
            logits[k] = lg[k] + ws[16 + k];
            mx = fmaxf(mx, logits[k]);
        }
        float sum = 0.0f;
        #pragma unroll
        for (int k = 0; k < 10; ++k) sum += __expf(logits[k] - mx);
        const float lse = mx + __logf(sum);
        float* o = out + (size_t)b * 10;
        #pragma unroll
        for (int k = 0; k < 10; k += 2) {
            const float2 v2 = make_float2(logits[k] - lse, logits[k + 1] - lse);
            *(float2*)(o + k) = v2;
        }
    }
}

extern "C" void kernel_launch(void* const* d_in, const int* in_sizes, int n_in,
                              void* d_out, int out_size, void* d_ws, size_t ws_size,
                              hipStream_t stream) {
    const float* x     = (const float*)d_in[0];
    const float* vp    = (const float*)d_in[1];
    const float* map_w = (const float*)d_in[2];
    const float* map_b = (const float*)d_in[3];
    const float* lin_w = (const float*)d_in[4];
    const float* lin_b = (const float*)d_in[5];
    float* out = (float*)d_out;
    float* ws  = (float*)d_ws;

    const int B = in_sizes[0] / 784;

    quanv_precompute<<<1, 256, 0, stream>>>(vp, map_w, map_b, lin_w, lin_b, ws);
    quanv_main<<<(B + 3) / 4, 256, 0, stream>>>(x, ws, out, B);
}

// Round 3
// 87.394 us; speedup vs baseline: 1.2540x; 1.1581x over previous
//
#include <hip/hip_runtime.h>

// ws float layout:
//   [0..3]  cva = cos(vp[0][i])     [4..7]  sva = sin(vp[0][i])
//   [8..11] cth = cos(vp[1][w])     [12..15] sth = sin(vp[1][w])
//   [16..25] folded bias b'[k] = lin_b[k] + sum_{p,j} lin_w[k,p*8+j]*map_b[j]
//   [32 .. 32+10*4*256) = M[k][i][p^]  (p^ in [0,256), zero for p^ >= 196)
//     M[k][i][p] = sum_j lin_w[k,p*8+j]*map_w[j*4+i]

#define WS_M   32
#define NWAVES 2048

__global__ __launch_bounds__(256) void quanv_pre(
    const float* __restrict__ vp,
    const float* __restrict__ map_w,
    const float* __restrict__ map_b,
    const float* __restrict__ lin_w,
    const float* __restrict__ lin_b,
    float* __restrict__ ws)
{
    const int k = blockIdx.x;    // 0..9 (one block per logit row)
    const int p = threadIdx.x;   // 0..255
    __shared__ float s_part[4];

    float pb = 0.0f;
    if (p < 196) {
        const float* lw = lin_w + k * 1568 + p * 8;
        const float4 w0 = *(const float4*)lw;
        const float4 w1 = *(const float4*)(lw + 4);
        const float l[8] = {w0.x, w0.y, w0.z, w0.w, w1.x, w1.y, w1.z, w1.w};
        float m[4] = {0.f, 0.f, 0.f, 0.f};
        #pragma unroll
        for (int j = 0; j < 8; ++j) {
            #pragma unroll
            for (int i = 0; i < 4; ++i)
                m[i] = fmaf(l[j], map_w[j * 4 + i], m[i]);
            pb = fmaf(l[j], map_b[j], pb);
        }
        #pragma unroll
        for (int i = 0; i < 4; ++i)
            ws[WS_M + (k * 4 + i) * 256 + p] = m[i];
    } else {
        #pragma unroll
        for (int i = 0; i < 4; ++i)
            ws[WS_M + (k * 4 + i) * 256 + p] = 0.0f;  // pad patches -> zero
    }

    // block-reduce pb for the folded bias
    #pragma unroll
    for (int off = 32; off; off >>= 1) pb += __shfl_xor(pb, off, 64);
    if ((p & 63) == 0) s_part[p >> 6] = pb;
    __syncthreads();
    if (p == 0)
        ws[16 + k] = lin_b[k] + s_part[0] + s_part[1] + s_part[2] + s_part[3];
    if (k == 0 && p < 4) {
        ws[p]      = cosf(vp[p]);
        ws[4 + p]  = sinf(vp[p]);
        ws[8 + p]  = cosf(vp[4 + p]);
        ws[12 + p] = sinf(vp[4 + p]);
    }
}

// One wave per image-stream: lane = patch (mod 64), M held in registers,
// 4 images per wave (B=8192 / 2048 waves). 2 waves/SIMD occupancy target.
__global__ __launch_bounds__(256, 2) void quanv_main(
    const float* __restrict__ x,
    const float* __restrict__ ws,
    float* __restrict__ out, int B)
{
    const int lane = threadIdx.x & 63;
    const int wave = blockIdx.x * 4 + (threadIdx.x >> 6);
    if (wave >= B) return;

    // wave-uniform params (scalar loads)
    float cva[4], sva[4], cth[4], sth[4];
    #pragma unroll
    for (int i = 0; i < 4; ++i) {
        cva[i] = ws[i];     sva[i] = ws[4 + i];
        cth[i] = ws[8 + i]; sth[i] = ws[12 + i];
    }
    float bias[10];
    #pragma unroll
    for (int k = 0; k < 10; ++k) bias[k] = ws[16 + k];

    // Preload this lane's M slice into registers: p^ = j*64 + lane.
    // Coalesced (lane-minor); j==3 rows are zero for lane >= 4.
    float Mr[10][4][4];
    #pragma unroll
    for (int k = 0; k < 10; ++k)
        #pragma unroll
        for (int i = 0; i < 4; ++i)
            #pragma unroll
            for (int j = 0; j < 4; ++j)
                Mr[k][i][j] = ws[WS_M + (k * 4 + i) * 256 + j * 64 + lane];

    // Fixed per-lane pixel offsets (clamped tail reads stay in-bounds;
    // their contributions are zeroed by the M padding).
    int off0[4], off1[4];
    #pragma unroll
    for (int j = 0; j < 4; ++j) {
        int p = j * 64 + lane;
        p = p > 195 ? 195 : p;
        const int py = p / 14;
        const int px = p - py * 14;
        off0[j] = py * 56 + px * 2;
        off1[j] = off0[j] + 28;
    }

    // software-pipelined pixel loads
    float2 nq0[4], nq1[4];
    {
        const float* img = x + (size_t)wave * 784;
        #pragma unroll
        for (int j = 0; j < 4; ++j) {
            nq0[j] = *(const float2*)(img + off0[j]);
            nq1[j] = *(const float2*)(img + off1[j]);
        }
    }

    for (int b = wave; b < B; b += NWAVES) {
        float2 q0[4], q1[4];
        #pragma unroll
        for (int j = 0; j < 4; ++j) { q0[j] = nq0[j]; q1[j] = nq1[j]; }

        int bn = b + NWAVES;
        bn = bn < B ? bn : b;   // last iter: reload current (harmless)
        {
            const float* img = x + (size_t)bn * 784;
            #pragma unroll
            for (int j = 0; j < 4; ++j) {
                nq0[j] = *(const float2*)(img + off0[j]);
                nq1[j] = *(const float2*)(img + off1[j]);
            }
        }

        float lg[10];
        #pragma unroll
        for (int k = 0; k < 10; ++k) lg[k] = 0.0f;

        #pragma unroll
        for (int j = 0; j < 4; ++j) {
            const float t[4] = {q0[j].x, q0[j].y, q1[j].x, q1[j].y};
            float C[4], S[4];
            #pragma unroll
            for (int i = 0; i < 4; ++i) {
                const float a  = t[i] * (1.0f / 255.0f);
                const float a2 = a * a;
                const float ct = fmaf(a2, -0.5f, 1.0f);         // cos(a), a<0.004
                const float st = a * fmaf(a2, -1.0f / 6.0f, 1.0f); // sin(a)
                C[i] = fmaf(cva[i], ct, -sva[i] * st);
                S[i] = fmaf(sva[i], ct,  cva[i] * st);
            }
            const float P1 = C[0] * C[1], P2 = P1 * C[2], P3 = P2 * C[3];
            const float m0 = fmaf(cth[0], C[0], -sth[0] * (S[0] * S[1]));
            const float m1 = fmaf(cth[1], P1,   -sth[1] * (S[1] * S[2]));
            const float m2 = fmaf(cth[2], P2,   -sth[2] * (S[2] * S[3]));
            const float m3 = fmaf(cth[3], P3,   -sth[3] * S[3]);
            #pragma unroll
            for (int k = 0; k < 10; ++k)
                lg[k] = fmaf(m0, Mr[k][0][j],
                        fmaf(m1, Mr[k][1][j],
                        fmaf(m2, Mr[k][2][j],
                        fmaf(m3, Mr[k][3][j], lg[k]))));
        }

        // wave butterfly reduction
        #pragma unroll
        for (int k = 0; k < 10; ++k) {
            float v = lg[k];
            #pragma unroll
            for (int off = 32; off; off >>= 1) v += __shfl_xor(v, off, 64);
            lg[k] = v;
        }

        if (lane == 0) {
            float logits[10], mx = -1e30f;
            #pragma unroll
            for (int k = 0; k < 10; ++k) {
                logits[k] = lg[k] + bias[k];
                mx = fmaxf(mx, logits[k]);
            }
            float sum = 0.0f;
            #pragma unroll
            for (int k = 0; k < 10; ++k) sum += __expf(logits[k] - mx);
            const float lse = mx + __logf(sum);
            float* o = out + (size_t)b * 10;
            #pragma unroll
            for (int k = 0; k < 10; k += 2)
                *(float2*)(o + k) = make_float2(logits[k] - lse,
                                                logits[k + 1] - lse);
        }
    }
}

extern "C" void kernel_launch(void* const* d_in, const int* in_sizes, int n_in,
                              void* d_out, int out_size, void* d_ws, size_t ws_size,
                              hipStream_t stream) {
    const float* x     = (const float*)d_in[0];
    const float* vp    = (const float*)d_in[1];
    const float* map_w = (const float*)d_in[2];
    const float* map_b = (const float*)d_in[3];
    const float* lin_w = (const float*)d_in[4];
    const float* lin_b = (const float*)d_in[5];
    float* out = (float*)d_out;
    float* ws  = (float*)d_ws;

    const int B = in_sizes[0] / 784;

    quanv_pre<<<10, 256, 0, stream>>>(vp, map_w, map_b, lin_w, lin_b, ws);
    quanv_main<<<NWAVES / 4, 256, 0, stream>>>(x, ws, out, B);
}

// Round 5
// 84.863 us; speedup vs baseline: 1.2914x; 1.0298x over previous
//
#include <hip/hip_runtime.h>

typedef _Float16 half2_t __attribute__((ext_vector_type(2)));

// ws float layout:
//   [0..3]  cva = cos(vp[0][i])     [4..7]   sva = sin(vp[0][i])
//   [8..11] cth = cos(vp[1][w])     [12..15] sth = sin(vp[1][w])
//   [16..25] folded bias b'[k] = lin_b[k] + sum_{p,j} lin_w[k,p*8+j]*map_b[j]
//   float offset 32: half2 M[(k*2+h)*256 + p], p in [0,196);
//     M[p][k][i] = sum_j lin_w[k,p*8+j]*map_w[j*4+i], f16;
//     p in [192,196) pre-scaled by 1/16 (16-lane-redundant tail trick).

#define WS_MOFF 32
#define NWAVES  2048

// ---------- helpers ----------
static __device__ __forceinline__ half2_t pk2(float a, float b) {
#if __has_builtin(__builtin_amdgcn_cvt_pkrtz)
    return __builtin_bit_cast(half2_t, __builtin_amdgcn_cvt_pkrtz(a, b));
#else
    half2_t r; r.x = (_Float16)a; r.y = (_Float16)b; return r;
#endif
}

static __device__ __forceinline__ float fdot2f(half2_t a, half2_t b, float c) {
#if __has_builtin(__builtin_amdgcn_fdot2)
    return __builtin_amdgcn_fdot2(a, b, c, false);
#else
    return c + (float)a.x * (float)b.x + (float)a.y * (float)b.y;
#endif
}

#if __has_builtin(__builtin_amdgcn_update_dpp)
template <int CTRL>
static __device__ __forceinline__ float dpp_add(float x) {
    int t = __builtin_amdgcn_update_dpp(0, __float_as_int(x), CTRL, 0xf, 0xf, false);
    return x + __int_as_float(t);
}
// canonical gfx9 wave64 sum; TOTAL lands in lane 63 (other lanes partial)
static __device__ __forceinline__ float wave_sum(float x) {
    x = dpp_add<0x111>(x);   // row_shr:1
    x = dpp_add<0x112>(x);   // row_shr:2
    x = dpp_add<0x114>(x);   // row_shr:4
    x = dpp_add<0x118>(x);   // row_shr:8
    x = dpp_add<0x142>(x);   // row_bcast:15
    x = dpp_add<0x143>(x);   // row_bcast:31
    return x;
}
#else
static __device__ __forceinline__ float wave_sum(float x) {
    #pragma unroll
    for (int off = 32; off; off >>= 1) x += __shfl_xor(x, off, 64);
    return x;   // every lane (incl. 63) holds the total
}
#endif

// ---------- precompute: fold map_w/map_b into lin_w, f16-pack M ----------
__global__ __launch_bounds__(256) void quanv_pre(
    const float* __restrict__ vp,
    const float* __restrict__ map_w,
    const float* __restrict__ map_b,
    const float* __restrict__ lin_w,
    const float* __restrict__ lin_b,
    float* __restrict__ ws)
{
    const int k = blockIdx.x;    // 0..9
    const int p = threadIdx.x;   // 0..255
    __shared__ float s_part[4];

    half2_t* Mws = (half2_t*)(ws + WS_MOFF);

    float pb = 0.0f;
    if (p < 196) {
        const float* lw = lin_w + k * 1568 + p * 8;
        const float4 w0 = *(const float4*)lw;
        const float4 w1 = *(const float4*)(lw + 4);
        const float l[8] = {w0.x, w0.y, w0.z, w0.w, w1.x, w1.y, w1.z, w1.w};
        float m[4] = {0.f, 0.f, 0.f, 0.f};
        #pragma unroll
        for (int j = 0; j < 8; ++j) {
            #pragma unroll
            for (int i = 0; i < 4; ++i)
                m[i] = fmaf(l[j], map_w[j * 4 + i], m[i]);
            pb = fmaf(l[j], map_b[j], pb);
        }
        const float sc = (p >= 192) ? 0.0625f : 1.0f;  // 16-lane-redundant tail
        Mws[(k * 2 + 0) * 256 + p] = pk2(m[0] * sc, m[1] * sc);
        Mws[(k * 2 + 1) * 256 + p] = pk2(m[2] * sc, m[3] * sc);
    }

    #pragma unroll
    for (int off = 32; off; off >>= 1) pb += __shfl_xor(pb, off, 64);
    if ((p & 63) == 0) s_part[p >> 6] = pb;
    __syncthreads();
    if (p == 0)
        ws[16 + k] = lin_b[k] + s_part[0] + s_part[1] + s_part[2] + s_part[3];
    if (k == 0 && p < 4) {
        ws[p]      = cosf(vp[p]);
        ws[4 + p]  = sinf(vp[p]);
        ws[8 + p]  = cosf(vp[4 + p]);
        ws[12 + p] = sinf(vp[4 + p]);
    }
}

// ---------- main: one wave per image-stream, M in f16 VGPRs ----------
__global__ __launch_bounds__(256, 3) void quanv_main(
    const float* __restrict__ x,
    const float* __restrict__ ws,
    float* __restrict__ out, int B)
{
    const int lane = threadIdx.x & 63;
    const int wave = blockIdx.x * 4 + (threadIdx.x >> 6);
    if (wave >= B) return;

    // wave-uniform params (scalar loads)
    float cva[4], sva[4], cth[4], sth[4];
    #pragma unroll
    for (int i = 0; i < 4; ++i) {
        cva[i] = ws[i];     sva[i] = ws[4 + i];
        cth[i] = ws[8 + i]; sth[i] = ws[12 + i];
    }

    // patch assignment: j<3 -> p=j*64+lane (0..191); j=3 -> 192+(lane&3)
    int pidx[4];
    #pragma unroll
    for (int j = 0; j < 3; ++j) pidx[j] = j * 64 + lane;
    pidx[3] = 192 + (lane & 3);

    // preload M fragments into VGPRs (80 half2 = 80 VGPRs), coalesced
    const half2_t* Mws = (const half2_t*)(ws + WS_MOFF);
    half2_t Mr[10][2][4];
    #pragma unroll
    for (int k = 0; k < 10; ++k)
        #pragma unroll
        for (int h = 0; h < 2; ++h)
            #pragma unroll
            for (int j = 0; j < 4; ++j)
                Mr[k][h][j] = Mws[(k * 2 + h) * 256 + pidx[j]];

    // fixed per-lane pixel offsets
    int off0[4], off1[4];
    #pragma unroll
    for (int j = 0; j < 4; ++j) {
        const int p  = pidx[j];
        const int py = p / 14;
        const int px = p - py * 14;
        off0[j] = py * 56 + px * 2;
        off1[j] = off0[j] + 28;
    }

    // software-pipelined pixel loads
    float2 nq0[4], nq1[4];
    {
        const float* img = x + (size_t)wave * 784;
        #pragma unroll
        for (int j = 0; j < 4; ++j) {
            nq0[j] = *(const float2*)(img + off0[j]);
            nq1[j] = *(const float2*)(img + off1[j]);
        }
    }

    for (int b = wave; b < B; b += NWAVES) {
        float2 q0[4], q1[4];
        #pragma unroll
        for (int j = 0; j < 4; ++j) { q0[j] = nq0[j]; q1[j] = nq1[j]; }

        int bn = b + NWAVES;
        bn = bn < B ? bn : b;
        {
            const float* img = x + (size_t)bn * 784;
            #pragma unroll
            for (int j = 0; j < 4; ++j) {
                nq0[j] = *(const float2*)(img + off0[j]);
                nq1[j] = *(const float2*)(img + off1[j]);
            }
        }

        float lg[10];
        #pragma unroll
        for (int k = 0; k < 10; ++k) lg[k] = 0.0f;

        #pragma unroll
        for (int j = 0; j < 4; ++j) {
            const float t[4] = {q0[j].x, q0[j].y, q1[j].x, q1[j].y};
            float C[4], S[4];
            #pragma unroll
            for (int i = 0; i < 4; ++i) {
                const float a  = t[i] * (1.0f / 255.0f);
                const float a2 = a * a;
                const float ct = fmaf(a2, -0.5f, 1.0f);            // cos a
                const float st = a * fmaf(a2, -1.0f / 6.0f, 1.0f); // sin a
                C[i] = fmaf(cva[i], ct, -sva[i] * st);
                S[i] = fmaf(sva[i], ct,  cva[i] * st);
            }
            const float P1 = C[0] * C[1], P2 = P1 * C[2], P3 = P2 * C[3];
            const float m0 = fmaf(cth[0], C[0], -sth[0] * (S[0] * S[1]));
            const float m1 = fmaf(cth[1], P1,   -sth[1] * (S[1] * S[2]));
            const float m2 = fmaf(cth[2], P2,   -sth[2] * (S[2] * S[3]));
            const float m3 = fmaf(cth[3], P3,   -sth[3] * S[3]);

            const half2_t h01 = pk2(m0, m1);
            const half2_t h23 = pk2(m2, m3);
            #pragma unroll
            for (int k = 0; k < 10; ++k)
                lg[k] = fdot2f(h01, Mr[k][0][j],
                         fdot2f(h23, Mr[k][1][j], lg[k]));
        }

        // DPP wave reduction: totals land in lane 63
        #pragma unroll
        for (int k = 0; k < 10; ++k) lg[k] = wave_sum(lg[k]);

        if (lane == 63) {
            float logits[10], mx = -1e30f;
            #pragma unroll
            for (int k = 0; k < 10; ++k) {
                logits[k] = lg[k] + ws[16 + k];
                mx = fmaxf(mx, logits[k]);
            }
            float sum = 0.0f;
            #pragma unroll
            for (int k = 0; k < 10; ++k) sum += __expf(logits[k] - mx);
            const float lse = mx + __logf(sum);
            float* o = out + (size_t)b * 10;
            #pragma unroll
            for (int k = 0; k < 10; k += 2)
                *(float2*)(o + k) = make_float2(logits[k] - lse,
                                                logits[k + 1] - lse);
        }
    }
}

extern "C" void kernel_launch(void* const* d_in, const int* in_sizes, int n_in,
                              void* d_out, int out_size, void* d_ws, size_t ws_size,
                              hipStream_t stream) {
    const float* x     = (const float*)d_in[0];
    const float* vp    = (const float*)d_in[1];
    const float* map_w = (const float*)d_in[2];
    const float* map_b = (const float*)d_in[3];
    const float* lin_w = (const float*)d_in[4];
    const float* lin_b = (const float*)d_in[5];
    float* out = (float*)d_out;
    float* ws  = (float*)d_ws;

    const int B = in_sizes[0] / 784;

    quanv_pre<<<10, 256, 0, stream>>>(vp, map_w, map_b, lin_w, lin_b, ws);
    quanv_main<<<NWAVES / 4, 256, 0, stream>>>(x, ws, out, B);
}